// Round 8
// baseline (248.224 us; speedup 1.0000x reference)
//
#include <hip/hip_runtime.h>
#include <stdint.h>

typedef float f32x4 __attribute__((ext_vector_type(4)));
typedef __bf16 bf16x8 __attribute__((ext_vector_type(8)));
typedef unsigned short u16x8 __attribute__((ext_vector_type(8)));

#define DEV __device__ __forceinline__

DEV unsigned short f2bf(float f) {
  unsigned int u = __float_as_uint(f);
  unsigned int r = (u + 0x7FFFu + ((u >> 16) & 1u)) >> 16;
  return (unsigned short)r;
}
DEV float b2f(unsigned short h) { return __uint_as_float(((unsigned int)h) << 16); }

DEV void gload16(const void* g, void* l) {
  __builtin_amdgcn_global_load_lds((__attribute__((address_space(1))) void*)(g),
                                   (__attribute__((address_space(3))) void*)(l), 16, 0, 0);
}

// ---------------- all casts fused: x (2M units) + 4 weights (512K units) ----
__global__ void cast_all(const float* __restrict__ x, const float* __restrict__ Wq,
                         const float* __restrict__ Wk, const float* __restrict__ Wv,
                         const float* __restrict__ Wo, unsigned short* __restrict__ xbf,
                         unsigned short* __restrict__ wqkv, unsigned short* __restrict__ wo) {
  int i = blockIdx.x * 256 + threadIdx.x;
  const float* src;
  unsigned short* dst;
  int j;
  if (i < 2097152) {
    src = x; dst = xbf; j = i;
  } else {
    int k = i - 2097152;           // 524288 units
    int sel = k >> 17; j = k & 131071;
    src = (sel == 0) ? Wq : (sel == 1) ? Wk : (sel == 2) ? Wv : Wo;
    dst = (sel < 3) ? (wqkv + (size_t)sel * 1048576) : wo;
  }
  const float4* p = (const float4*)src + (size_t)j * 2;
  float4 a = p[0], b = p[1];
  u16x8 o;
  o[0] = f2bf(a.x); o[1] = f2bf(a.y); o[2] = f2bf(a.z); o[3] = f2bf(a.w);
  o[4] = f2bf(b.x); o[5] = f2bf(b.y); o[6] = f2bf(b.z); o[7] = f2bf(b.w);
  ((u16x8*)dst)[j] = o;
}

// ---------------- bf16 GEMM, B^T layout (out[m,n] = sum_k A[m,k]*W[n,k]) ----
// 128x128 tile, BK=64, multi-block/CU implicit overlap. No XCD swizzle
// (r4/r5 A/B: swizzle FETCH 143->210MB, +3.5% time). A bf16 via gload_lds
// (r6 A/B: fp32 reg-staged fused cast = 104->180us regression).
template<int MODE>
__global__ __launch_bounds__(256, 2) void gemm_bt(
    const unsigned short* __restrict__ A, const unsigned short* __restrict__ Bw,
    void* __restrict__ out0, unsigned short* __restrict__ qp,
    unsigned short* __restrict__ kp, unsigned short* __restrict__ vp,
    int K, int N, int nTn)
{
  __shared__ unsigned short sA[128 * 64];
  __shared__ unsigned short sB[128 * 64];
  int t = threadIdx.x, w = t >> 6, lane = t & 63, fr = lane & 15, fq = lane >> 4;
  int bid = blockIdx.x;
  int bm = bid / nTn, bn = bid % nTn;
  int wm = w >> 1, wn = w & 1;

  f32x4 acc[4][4];
  f32x4 z4 = {0.f, 0.f, 0.f, 0.f};
#pragma unroll
  for (int mi = 0; mi < 4; ++mi)
#pragma unroll
    for (int ni = 0; ni < 4; ++ni) acc[mi][ni] = z4;

  for (int k0 = 0; k0 < K; k0 += 64) {
#pragma unroll
    for (int i = 0; i < 4; ++i) {
      int p = (i * 4 + w) * 64 + lane;
      int r = p >> 3;
      int c8 = (p & 7) ^ (r & 7);  // inverse-swizzled source column-chunk
      gload16(A + (size_t)(bm * 128 + r) * K + k0 + c8 * 8, &sA[(i * 4 + w) * 512]);
      gload16(Bw + (size_t)(bn * 128 + r) * K + k0 + c8 * 8, &sB[(i * 4 + w) * 512]);
    }
    __syncthreads();
#pragma unroll
    for (int ks = 0; ks < 2; ++ks) {
      bf16x8 af[4], bg[4];
#pragma unroll
      for (int mi = 0; mi < 4; ++mi) {
        int r = wm * 64 + mi * 16 + fr;
        int c8 = (ks * 4 + fq) ^ (r & 7);
        af[mi] = *(const bf16x8*)&sA[(r * 8 + c8) * 8];
      }
#pragma unroll
      for (int ni = 0; ni < 4; ++ni) {
        int r = wn * 64 + ni * 16 + fr;
        int c8 = (ks * 4 + fq) ^ (r & 7);
        bg[ni] = *(const bf16x8*)&sB[(r * 8 + c8) * 8];
      }
#pragma unroll
      for (int mi = 0; mi < 4; ++mi)
#pragma unroll
        for (int ni = 0; ni < 4; ++ni)
          acc[mi][ni] = __builtin_amdgcn_mfma_f32_16x16x32_bf16(af[mi], bg[ni], acc[mi][ni], 0, 0, 0);
    }
    __syncthreads();
  }

  if (MODE == 0) {
    float* O = (float*)out0;
#pragma unroll
    for (int mi = 0; mi < 4; ++mi)
#pragma unroll
      for (int ni = 0; ni < 4; ++ni)
#pragma unroll
        for (int j = 0; j < 4; ++j) {
          int m = bm * 128 + wm * 64 + mi * 16 + fq * 4 + j;
          int n = bn * 128 + wn * 64 + ni * 16 + fr;
          O[(size_t)m * N + n] = acc[mi][ni][j];
        }
  } else {
    int tsel = (bn * 128) >> 10;  // 0:Q 1:K 2:V (whole block in one tensor)
    unsigned short* base = (tsel == 0) ? qp : ((tsel == 1) ? kp : vp);
#pragma unroll
    for (int mi = 0; mi < 4; ++mi)
#pragma unroll
      for (int ni = 0; ni < 4; ++ni)
#pragma unroll
        for (int j = 0; j < 4; ++j) {
          int m = bm * 128 + wm * 64 + mi * 16 + fq * 4 + j;  // b*4096 + l
          int n = bn * 128 + wn * 64 + ni * 16 + fr;
          int col1 = n & 1023;
          int h = col1 >> 6, d = col1 & 63;
          int b = m >> 12, l = m & 4095;
          float v = acc[mi][ni][j];
          if (tsel < 2) v = (v > 0.f) ? (v + 1.f) : __expf(v);  // elu(v)+1
          base[(((size_t)(b * 16 + h)) * 4096 + l) * 64 + d] = f2bf(v);
        }
  }
}

// ---------------- pass 1: per-chunk state via MFMA ---------------------------
// S_c[e][d] = sum_s v[s][e]*k[s][d]  (stored Sbuf[bh][c][e][d]); z_c[d] = sum_s k[s][d]
// Staging: r4 version (vector u16x8 global loads; scalar LDS transpose writes).
// r7's 64-scalar-u16-global-load variant regressed ~10us (8x VMEM instrs).
__global__ __launch_bounds__(256) void chunk_state(
    const unsigned short* __restrict__ kb, const unsigned short* __restrict__ vb,
    float* __restrict__ Sbuf, float* __restrict__ zbuf)
{
  __shared__ unsigned short kT[64 * 136];
  __shared__ unsigned short vT[64 * 136];
  int t = threadIdx.x, w = t >> 6, lane = t & 63, fr = lane & 15, fq = lane >> 4;
  int bh = blockIdx.x >> 5, c = blockIdx.x & 31;
  size_t base = ((size_t)bh * 4096 + (size_t)c * 128) * 64;

  int s = t >> 1, d0 = (t & 1) * 32;
  const unsigned short* kpp = kb + base + (size_t)s * 64 + d0;
  const unsigned short* vpp = vb + base + (size_t)s * 64 + d0;
#pragma unroll
  for (int i = 0; i < 4; ++i) {
    u16x8 kr = *(const u16x8*)(kpp + i * 8);
    u16x8 vr = *(const u16x8*)(vpp + i * 8);
#pragma unroll
    for (int j = 0; j < 8; ++j) {
      int d = d0 + i * 8 + j;
      kT[d * 136 + s] = kr[j];
      vT[d * 136 + s] = vr[j];
    }
  }
  __syncthreads();

  f32x4 acc[4];
  f32x4 z4 = {0.f, 0.f, 0.f, 0.f};
#pragma unroll
  for (int n = 0; n < 4; ++n) acc[n] = z4;
#pragma unroll
  for (int ks = 0; ks < 4; ++ks) {
    bf16x8 av = *(const bf16x8*)&vT[(w * 16 + fr) * 136 + ks * 32 + fq * 8];
#pragma unroll
    for (int n = 0; n < 4; ++n) {
      bf16x8 bk = *(const bf16x8*)&kT[(n * 16 + fr) * 136 + ks * 32 + fq * 8];
      acc[n] = __builtin_amdgcn_mfma_f32_16x16x32_bf16(av, bk, acc[n], 0, 0, 0);
    }
  }
  size_t ob = ((size_t)bh * 32 + c) * 4096;
#pragma unroll
  for (int n = 0; n < 4; ++n)
#pragma unroll
    for (int j = 0; j < 4; ++j) {
      int e = w * 16 + fq * 4 + j, dd = n * 16 + fr;
      Sbuf[ob + (size_t)e * 64 + dd] = acc[n][j];
    }
  if (t < 64) {
    float z = 0.f;
#pragma unroll
    for (int i = 0; i < 16; ++i) {
      u16x8 kr = *(const u16x8*)&kT[t * 136 + i * 8];
#pragma unroll
      for (int j = 0; j < 8; ++j) z += b2f(kr[j]);
    }
    zbuf[((size_t)bh * 32 + c) * 64 + t] = z;
  }
}

// ---------------- pass 2: parallel exclusive prefix (S blocks then z blocks) -
__global__ __launch_bounds__(256) void scan_all(
    const float* __restrict__ Sbuf, const float* __restrict__ zbuf,
    unsigned short* __restrict__ Spref, float* __restrict__ zpref)
{
  if (blockIdx.x < 1024) {
    int idx = blockIdx.x * 256 + threadIdx.x;  // 262144 sequences
    int bh = idx >> 12, i = idx & 4095;
    size_t base = (size_t)bh * 32 * 4096 + i;
    float run = 0.f;
#pragma unroll
    for (int c = 0; c < 32; ++c) {
      float v = Sbuf[base + (size_t)c * 4096];
      Spref[base + (size_t)c * 4096] = f2bf(run);
      run += v;
    }
  } else {
    int idx = (blockIdx.x - 1024) * 256 + threadIdx.x;  // 4096 sequences
    size_t base = (size_t)(idx >> 6) * 32 * 64 + (idx & 63);
    float run = 0.f;
#pragma unroll
    for (int c = 0; c < 32; ++c) {
      float v = zbuf[base + c * 64];
      zpref[base + c * 64] = run;
      run += v;
    }
  }
}

// ---------------- pass 3: per-chunk output ----------------------------------
// v3: swapped QK^T with q,k fragments loaded DIRECTLY from global (row-contig
// u16x8, L1/L2-hot) -> no q/k LDS staging, skv holds only v^T, and the whole
// kernel needs ONE barrier: {v->regs, sS stage, v^T scatter, QK^T, mask+rowsum,
// P->ss} | barrier | {q@S, P@v, den, store}.
__global__ __launch_bounds__(256, 2) void chunk_out(
    const unsigned short* __restrict__ qb, const unsigned short* __restrict__ kb,
    const unsigned short* __restrict__ vb, const unsigned short* __restrict__ Spref,
    const float* __restrict__ zpref, unsigned short* __restrict__ attn)
{
  __shared__ unsigned short skv[64 * 128];  // v^T [e][s] (swz &15)
  __shared__ unsigned short ss[128 * 128];  // P bf16 [m][s] (swz &15)
  __shared__ unsigned short sS[80 * 64];    // state rows e=0..63, z at 64, zeros 65..79
  int t = threadIdx.x, w = t >> 6, lane = t & 63, fr = lane & 15, fq = lane >> 4;
  int bh = blockIdx.x >> 5, c = blockIdx.x & 31;
  size_t qkbase = ((size_t)bh * 4096 + (size_t)c * 128) * 64;
  size_t sbase = ((size_t)bh * 32 + c) * 4096;

  u16x8 vreg[4];  // v chunk staged to regs early (T14-style)
#pragma unroll
  for (int i = 0; i < 4; ++i)
    vreg[i] = *(const u16x8*)(vb + qkbase + (size_t)(t * 4 + i) * 8);

  // sS staging (Spref rows [e][d] bf16 + z row 64 + zero rows 65..79)
#pragma unroll
  for (int i = 0; i < 2; ++i) {
    int p = t * 2 + i, e = p >> 3, c8 = p & 7;
    *(u16x8*)&sS[(e * 8 + (c8 ^ (e & 7))) * 8] = *(const u16x8*)(Spref + sbase + (size_t)p * 8);
  }
  if (t < 64) sS[64 * 64 + t] = f2bf(zpref[((size_t)bh * 32 + c) * 64 + t]);
  {
    unsigned int* zz = (unsigned int*)&sS[65 * 64];
    for (int i = t; i < 480; i += 256) zz[i] = 0u;
  }

  // v^T scatter into skv (row e, col s; swizzle &15) — LDS write only
#pragma unroll
  for (int i = 0; i < 4; ++i) {
    int p = t * 4 + i, s = p >> 3, e0g = (p & 7) * 8;
#pragma unroll
    for (int j = 0; j < 8; ++j) {
      int e = e0g + j;
      skv[(e * 16 + ((s >> 3) ^ (e & 15))) * 8 + (s & 7)] = vreg[i][j];
    }
  }

  int rowbase = w * 32;
  // q fragments direct from global: lane needs q[row][kt*32 + fq*8 .. +7]
  bf16x8 aq[2][2];
#pragma unroll
  for (int mi = 0; mi < 2; ++mi)
#pragma unroll
    for (int kt = 0; kt < 2; ++kt) {
      int r = rowbase + mi * 16 + fr;
      aq[mi][kt] = *(const bf16x8*)(qb + qkbase + (size_t)r * 64 + kt * 32 + fq * 8);
    }

  // swapped QK^T (k fragments direct from global): accsT[mi][ni] = C[s][m]
  f32x4 accsT[2][8];
  f32x4 z4 = {0.f, 0.f, 0.f, 0.f};
#pragma unroll
  for (int mi = 0; mi < 2; ++mi)
#pragma unroll
    for (int ni = 0; ni < 8; ++ni) accsT[mi][ni] = z4;

#pragma unroll
  for (int ni = 0; ni < 8; ++ni)
#pragma unroll
    for (int kt = 0; kt < 2; ++kt) {
      int r = ni * 16 + fr;
      bf16x8 bk = *(const bf16x8*)(kb + qkbase + (size_t)r * 64 + kt * 32 + fq * 8);
      accsT[0][ni] = __builtin_amdgcn_mfma_f32_16x16x32_bf16(bk, aq[0][kt], accsT[0][ni], 0, 0, 0);
      accsT[1][ni] = __builtin_amdgcn_mfma_f32_16x16x32_bf16(bk, aq[1][kt], accsT[1][ni], 0, 0, 0);
    }

  // in-register causal mask + rowsum (per lane: m = rowbase+mi*16+fr)
  float rs[2];
#pragma unroll
  for (int mi = 0; mi < 2; ++mi) {
    int m16 = mi * 16 + fr;        // m - rowbase
    float sum = 0.f;
#pragma unroll
    for (int ni = 0; ni < 8; ++ni)
#pragma unroll
      for (int j = 0; j < 4; ++j) {
        int s = ni * 16 + fq * 4 + j - rowbase;  // s - rowbase
        float v = (s <= m16) ? accsT[mi][ni][j] : 0.f;
        accsT[mi][ni][j] = v;
        sum += v;
      }
    sum += __shfl_xor(sum, 16, 64);
    sum += __shfl_xor(sum, 32, 64);
    rs[mi] = sum;
  }

  // P -> ss as packed b32 pairs: addr chunk (2ni+(fq>>1))^(m&15), off (fq&1)*4+2p
#pragma unroll
  for (int mi = 0; mi < 2; ++mi) {
    int m = rowbase + mi * 16 + fr;
#pragma unroll
    for (int ni = 0; ni < 8; ++ni)
#pragma unroll
      for (int p = 0; p < 2; ++p) {
        unsigned int pk = (unsigned int)f2bf(accsT[mi][ni][2 * p]) |
                          ((unsigned int)f2bf(accsT[mi][ni][2 * p + 1]) << 16);
        int chunk = (2 * ni + (fq >> 1)) ^ (m & 15);
        *(unsigned int*)&ss[m * 128 + chunk * 8 + (fq & 1) * 4 + 2 * p] = pk;
      }
  }
  __syncthreads();  // single barrier: skv/ss/sS all written

  f32x4 acco[2][4];
  f32x4 accd[2];
#pragma unroll
  for (int mi = 0; mi < 2; ++mi) {
    accd[mi] = z4;
#pragma unroll
    for (int ni = 0; ni < 4; ++ni) acco[mi][ni] = z4;
  }
  // inter-chunk: q @ S (+ den column from z row)
#pragma unroll
  for (int kt = 0; kt < 2; ++kt) {
#pragma unroll
    for (int ni = 0; ni < 4; ++ni) {
      int r = ni * 16 + fr;
      int c8 = (kt * 4 + fq) ^ (r & 7);
      bf16x8 bS = *(const bf16x8*)&sS[(r * 8 + c8) * 8];
      acco[0][ni] = __builtin_amdgcn_mfma_f32_16x16x32_bf16(aq[0][kt], bS, acco[0][ni], 0, 0, 0);
      acco[1][ni] = __builtin_amdgcn_mfma_f32_16x16x32_bf16(aq[1][kt], bS, acco[1][ni], 0, 0, 0);
    }
    {
      int r = 64 + fr;
      int c8 = (kt * 4 + fq) ^ (r & 7);
      bf16x8 bz = *(const bf16x8*)&sS[(r * 8 + c8) * 8];
      accd[0] = __builtin_amdgcn_mfma_f32_16x16x32_bf16(aq[0][kt], bz, accd[0], 0, 0, 0);
      accd[1] = __builtin_amdgcn_mfma_f32_16x16x32_bf16(aq[1][kt], bz, accd[1], 0, 0, 0);
    }
  }
  // intra-chunk: masked P @ v
#pragma unroll
  for (int kt = 0; kt < 4; ++kt) {
    bf16x8 am[2];
#pragma unroll
    for (int mi = 0; mi < 2; ++mi) {
      int r = rowbase + mi * 16 + fr;
      int c8 = (kt * 4 + fq) ^ (r & 15);
      am[mi] = *(const bf16x8*)&ss[(r * 16 + c8) * 8];
    }
#pragma unroll
    for (int ni = 0; ni < 4; ++ni) {
      int r = ni * 16 + fr;
      int c8 = (kt * 4 + fq) ^ (r & 15);
      bf16x8 bv = *(const bf16x8*)&skv[(r * 16 + c8) * 8];
      acco[0][ni] = __builtin_amdgcn_mfma_f32_16x16x32_bf16(am[0], bv, acco[0][ni], 0, 0, 0);
      acco[1][ni] = __builtin_amdgcn_mfma_f32_16x16x32_bf16(am[1], bv, acco[1][ni], 0, 0, 0);
    }
  }

  int b = bh >> 4, h = bh & 15;
#pragma unroll
  for (int mi = 0; mi < 2; ++mi)
#pragma unroll
    for (int j = 0; j < 4; ++j) {
      float rsj = __shfl(rs[mi], fq * 4 + j, 64);  // rowsum for m16 = fq*4+j
      float den = __shfl(accd[mi][j], (lane & 48), 64) + rsj;
      float rden = 1.f / den;
      int m = rowbase + mi * 16 + fq * 4 + j;
      size_t rowoff = ((size_t)b * 4096 + (size_t)c * 128 + m) * 1024 + h * 64;
#pragma unroll
      for (int ni = 0; ni < 4; ++ni) {
        int e = ni * 16 + fr;
        float o = acco[mi][ni][j] * rden + 1e-12f;
        attn[rowoff + e] = f2bf(o);
      }
    }
}

// ---------------- host launch ------------------------------------------------
extern "C" void kernel_launch(void* const* d_in, const int* in_sizes, int n_in,
                              void* d_out, int out_size, void* d_ws, size_t ws_size,
                              hipStream_t stream) {
  (void)in_sizes; (void)n_in; (void)out_size; (void)ws_size;
  const float* x = (const float*)d_in[0];
  const float* Wq = (const float*)d_in[1];
  const float* Wk = (const float*)d_in[2];
  const float* Wv = (const float*)d_in[3];
  const float* Wo = (const float*)d_in[4];
  char* ws = (char*)d_ws;
  unsigned short* xbf  = (unsigned short*)(ws + 0);          // 33554432 B
  unsigned short* wqkv = (unsigned short*)(ws + 33554432);   // 6291456 B
  unsigned short* wo   = (unsigned short*)(ws + 39845888);   // 2097152 B
  unsigned short* q    = (unsigned short*)(ws + 41943040);   // 33554432 B
  unsigned short* k    = (unsigned short*)(ws + 75497472);   // 33554432 B
  unsigned short* v    = (unsigned short*)(ws + 109051904);  // 33554432 B
  unsigned short* attn = (unsigned short*)(ws + 142606336);  // 33554432 B
  float* Sbuf          = (float*)(ws + 176160768);           // 33554432 B
  unsigned short* Spref= (unsigned short*)(ws + 209715200);  // 16777216 B
  float* zbuf          = (float*)(ws + 226492416);           // 524288 B
  float* zpref         = (float*)(ws + 227016704);           // 524288 B

  cast_all<<<10240, 256, 0, stream>>>(x, Wq, Wk, Wv, Wo, xbf, wqkv, wo);
  gemm_bt<1><<<3072, 256, 0, stream>>>(xbf, wqkv, nullptr, q, k, v, 1024, 3072, 24);
  chunk_state<<<2048, 256, 0, stream>>>(k, v, Sbuf, zbuf);
  scan_all<<<1040, 256, 0, stream>>>(Sbuf, zbuf, Spref, zpref);
  chunk_out<<<2048, 256, 0, stream>>>(q, k, v, Spref, zpref, attn);
  gemm_bt<0><<<1024, 256, 0, stream>>>(attn, wo, d_out, nullptr, nullptr, nullptr, 1024, 1024, 8);
}

// Round 9
// 241.359 us; speedup vs baseline: 1.0284x; 1.0284x over previous
//
#include <hip/hip_runtime.h>
#include <stdint.h>

typedef float f32x4 __attribute__((ext_vector_type(4)));
typedef __bf16 bf16x8 __attribute__((ext_vector_type(8)));
typedef unsigned short u16x8 __attribute__((ext_vector_type(8)));

#define DEV __device__ __forceinline__

DEV unsigned short f2bf(float f) {
  unsigned int u = __float_as_uint(f);
  unsigned int r = (u + 0x7FFFu + ((u >> 16) & 1u)) >> 16;
  return (unsigned short)r;
}
DEV float b2f(unsigned short h) { return __uint_as_float(((unsigned int)h) << 16); }

DEV void gload16(const void* g, void* l) {
  __builtin_amdgcn_global_load_lds((__attribute__((address_space(1))) void*)(g),
                                   (__attribute__((address_space(3))) void*)(l), 16, 0, 0);
}

// ---------------- all casts fused: x (2M units) + 4 weights (512K units) ----
__global__ void cast_all(const float* __restrict__ x, const float* __restrict__ Wq,
                         const float* __restrict__ Wk, const float* __restrict__ Wv,
                         const float* __restrict__ Wo, unsigned short* __restrict__ xbf,
                         unsigned short* __restrict__ wqkv, unsigned short* __restrict__ wo) {
  int i = blockIdx.x * 256 + threadIdx.x;
  const float* src;
  unsigned short* dst;
  int j;
  if (i < 2097152) {
    src = x; dst = xbf; j = i;
  } else {
    int k = i - 2097152;           // 524288 units
    int sel = k >> 17; j = k & 131071;
    src = (sel == 0) ? Wq : (sel == 1) ? Wk : (sel == 2) ? Wv : Wo;
    dst = (sel < 3) ? (wqkv + (size_t)sel * 1048576) : wo;
  }
  const float4* p = (const float4*)src + (size_t)j * 2;
  float4 a = p[0], b = p[1];
  u16x8 o;
  o[0] = f2bf(a.x); o[1] = f2bf(a.y); o[2] = f2bf(a.z); o[3] = f2bf(a.w);
  o[4] = f2bf(b.x); o[5] = f2bf(b.y); o[6] = f2bf(b.z); o[7] = f2bf(b.w);
  ((u16x8*)dst)[j] = o;
}

// ---------------- bf16 GEMM, B^T layout (out[m,n] = sum_k A[m,k]*W[n,k]) ----
// 128x128 tile, BK=64, multi-block/CU implicit overlap. No XCD swizzle
// (r4/r5 A/B: swizzle FETCH 143->210MB, +3.5% time). A bf16 via gload_lds
// (r6 A/B: fp32 reg-staged fused cast = 104->180us regression).
template<int MODE>
__global__ __launch_bounds__(256, 2) void gemm_bt(
    const unsigned short* __restrict__ A, const unsigned short* __restrict__ Bw,
    void* __restrict__ out0, unsigned short* __restrict__ qp,
    unsigned short* __restrict__ kp, unsigned short* __restrict__ vp,
    int K, int N, int nTn)
{
  __shared__ unsigned short sA[128 * 64];
  __shared__ unsigned short sB[128 * 64];
  int t = threadIdx.x, w = t >> 6, lane = t & 63, fr = lane & 15, fq = lane >> 4;
  int bid = blockIdx.x;
  int bm = bid / nTn, bn = bid % nTn;
  int wm = w >> 1, wn = w & 1;

  f32x4 acc[4][4];
  f32x4 z4 = {0.f, 0.f, 0.f, 0.f};
#pragma unroll
  for (int mi = 0; mi < 4; ++mi)
#pragma unroll
    for (int ni = 0; ni < 4; ++ni) acc[mi][ni] = z4;

  for (int k0 = 0; k0 < K; k0 += 64) {
#pragma unroll
    for (int i = 0; i < 4; ++i) {
      int p = (i * 4 + w) * 64 + lane;
      int r = p >> 3;
      int c8 = (p & 7) ^ (r & 7);  // inverse-swizzled source column-chunk
      gload16(A + (size_t)(bm * 128 + r) * K + k0 + c8 * 8, &sA[(i * 4 + w) * 512]);
      gload16(Bw + (size_t)(bn * 128 + r) * K + k0 + c8 * 8, &sB[(i * 4 + w) * 512]);
    }
    __syncthreads();
#pragma unroll
    for (int ks = 0; ks < 2; ++ks) {
      bf16x8 af[4], bg[4];
#pragma unroll
      for (int mi = 0; mi < 4; ++mi) {
        int r = wm * 64 + mi * 16 + fr;
        int c8 = (ks * 4 + fq) ^ (r & 7);
        af[mi] = *(const bf16x8*)&sA[(r * 8 + c8) * 8];
      }
#pragma unroll
      for (int ni = 0; ni < 4; ++ni) {
        int r = wn * 64 + ni * 16 + fr;
        int c8 = (ks * 4 + fq) ^ (r & 7);
        bg[ni] = *(const bf16x8*)&sB[(r * 8 + c8) * 8];
      }
#pragma unroll
      for (int mi = 0; mi < 4; ++mi)
#pragma unroll
        for (int ni = 0; ni < 4; ++ni)
          acc[mi][ni] = __builtin_amdgcn_mfma_f32_16x16x32_bf16(af[mi], bg[ni], acc[mi][ni], 0, 0, 0);
    }
    __syncthreads();
  }

  if (MODE == 0) {
    float* O = (float*)out0;
#pragma unroll
    for (int mi = 0; mi < 4; ++mi)
#pragma unroll
      for (int ni = 0; ni < 4; ++ni)
#pragma unroll
        for (int j = 0; j < 4; ++j) {
          int m = bm * 128 + wm * 64 + mi * 16 + fq * 4 + j;
          int n = bn * 128 + wn * 64 + ni * 16 + fr;
          O[(size_t)m * N + n] = acc[mi][ni][j];
        }
  } else {
    int tsel = (bn * 128) >> 10;  // 0:Q 1:K 2:V (whole block in one tensor)
    unsigned short* base = (tsel == 0) ? qp : ((tsel == 1) ? kp : vp);
#pragma unroll
    for (int mi = 0; mi < 4; ++mi)
#pragma unroll
      for (int ni = 0; ni < 4; ++ni)
#pragma unroll
        for (int j = 0; j < 4; ++j) {
          int m = bm * 128 + wm * 64 + mi * 16 + fq * 4 + j;  // b*4096 + l
          int n = bn * 128 + wn * 64 + ni * 16 + fr;
          int col1 = n & 1023;
          int h = col1 >> 6, d = col1 & 63;
          int b = m >> 12, l = m & 4095;
          float v = acc[mi][ni][j];
          if (tsel < 2) v = (v > 0.f) ? (v + 1.f) : __expf(v);  // elu(v)+1
          base[(((size_t)(b * 16 + h)) * 4096 + l) * 64 + d] = f2bf(v);
        }
  }
}

// ---------------- pass 1: per-chunk state via MFMA ---------------------------
// S_c[e][d] = sum_s v[s][e]*k[s][d]  (stored Sbuf[bh][c][e][d]); z_c[d] = sum_s k[s][d]
// Staging: r4 version (vector u16x8 global loads; scalar LDS transpose writes).
// r7's 64-scalar-u16-global-load variant regressed ~10us (8x VMEM instrs).
__global__ __launch_bounds__(256) void chunk_state(
    const unsigned short* __restrict__ kb, const unsigned short* __restrict__ vb,
    float* __restrict__ Sbuf, float* __restrict__ zbuf)
{
  __shared__ unsigned short kT[64 * 136];
  __shared__ unsigned short vT[64 * 136];
  int t = threadIdx.x, w = t >> 6, lane = t & 63, fr = lane & 15, fq = lane >> 4;
  int bh = blockIdx.x >> 5, c = blockIdx.x & 31;
  size_t base = ((size_t)bh * 4096 + (size_t)c * 128) * 64;

  int s = t >> 1, d0 = (t & 1) * 32;
  const unsigned short* kpp = kb + base + (size_t)s * 64 + d0;
  const unsigned short* vpp = vb + base + (size_t)s * 64 + d0;
#pragma unroll
  for (int i = 0; i < 4; ++i) {
    u16x8 kr = *(const u16x8*)(kpp + i * 8);
    u16x8 vr = *(const u16x8*)(vpp + i * 8);
#pragma unroll
    for (int j = 0; j < 8; ++j) {
      int d = d0 + i * 8 + j;
      kT[d * 136 + s] = kr[j];
      vT[d * 136 + s] = vr[j];
    }
  }
  __syncthreads();

  f32x4 acc[4];
  f32x4 z4 = {0.f, 0.f, 0.f, 0.f};
#pragma unroll
  for (int n = 0; n < 4; ++n) acc[n] = z4;
#pragma unroll
  for (int ks = 0; ks < 4; ++ks) {
    bf16x8 av = *(const bf16x8*)&vT[(w * 16 + fr) * 136 + ks * 32 + fq * 8];
#pragma unroll
    for (int n = 0; n < 4; ++n) {
      bf16x8 bk = *(const bf16x8*)&kT[(n * 16 + fr) * 136 + ks * 32 + fq * 8];
      acc[n] = __builtin_amdgcn_mfma_f32_16x16x32_bf16(av, bk, acc[n], 0, 0, 0);
    }
  }
  size_t ob = ((size_t)bh * 32 + c) * 4096;
#pragma unroll
  for (int n = 0; n < 4; ++n)
#pragma unroll
    for (int j = 0; j < 4; ++j) {
      int e = w * 16 + fq * 4 + j, dd = n * 16 + fr;
      Sbuf[ob + (size_t)e * 64 + dd] = acc[n][j];
    }
  if (t < 64) {
    float z = 0.f;
#pragma unroll
    for (int i = 0; i < 16; ++i) {
      u16x8 kr = *(const u16x8*)&kT[t * 136 + i * 8];
#pragma unroll
      for (int j = 0; j < 8; ++j) z += b2f(kr[j]);
    }
    zbuf[((size_t)bh * 32 + c) * 64 + t] = z;
  }
}

// ---------------- pass 2: parallel exclusive prefix (S blocks then z blocks) -
__global__ __launch_bounds__(256) void scan_all(
    const float* __restrict__ Sbuf, const float* __restrict__ zbuf,
    unsigned short* __restrict__ Spref, float* __restrict__ zpref)
{
  if (blockIdx.x < 1024) {
    int idx = blockIdx.x * 256 + threadIdx.x;  // 262144 sequences
    int bh = idx >> 12, i = idx & 4095;
    size_t base = (size_t)bh * 32 * 4096 + i;
    float run = 0.f;
#pragma unroll
    for (int c = 0; c < 32; ++c) {
      float v = Sbuf[base + (size_t)c * 4096];
      Spref[base + (size_t)c * 4096] = f2bf(run);
      run += v;
    }
  } else {
    int idx = (blockIdx.x - 1024) * 256 + threadIdx.x;  // 4096 sequences
    size_t base = (size_t)(idx >> 6) * 32 * 64 + (idx & 63);
    float run = 0.f;
#pragma unroll
    for (int c = 0; c < 32; ++c) {
      float v = zbuf[base + c * 64];
      zpref[base + c * 64] = run;
      run += v;
    }
  }
}

// ---------------- pass 3: per-chunk output ----------------------------------
// v4 = v2 with: (a) k kept in LDS (v3's k-from-global was the +16us fault),
// (b) q fragments direct from global (no sharing lost: 1 wave per q-row),
// (c) v^T gets its own region (svt) so its scatter moves before barrier 1
// -> 2 barriers instead of v2's 3, sq buffer eliminated.
__global__ __launch_bounds__(256, 2) void chunk_out(
    const unsigned short* __restrict__ qb, const unsigned short* __restrict__ kb,
    const unsigned short* __restrict__ vb, const unsigned short* __restrict__ Spref,
    const float* __restrict__ zpref, unsigned short* __restrict__ attn)
{
  __shared__ unsigned short sk[128 * 64];   // k, swizzled (&7)
  __shared__ unsigned short svt[64 * 128];  // v^T [e][s] (swz &15)
  __shared__ unsigned short ss[128 * 128];  // P bf16 [m][s] (swz &15)
  __shared__ unsigned short sS[80 * 64];    // state rows e=0..63, z at 64, zeros 65..79
  int t = threadIdx.x, w = t >> 6, lane = t & 63, fr = lane & 15, fq = lane >> 4;
  int bh = blockIdx.x >> 5, c = blockIdx.x & 31;
  size_t qkbase = ((size_t)bh * 4096 + (size_t)c * 128) * 64;
  size_t sbase = ((size_t)bh * 32 + c) * 4096;

  u16x8 vreg[4];  // v chunk -> regs -> v^T scatter (all pre-barrier)
#pragma unroll
  for (int i = 0; i < 4; ++i)
    vreg[i] = *(const u16x8*)(vb + qkbase + (size_t)(t * 4 + i) * 8);

  // k staging (swz &7)
#pragma unroll
  for (int i = 0; i < 4; ++i) {
    int p = t * 4 + i, r = p >> 3, c8 = p & 7;
    *(u16x8*)&sk[(r * 8 + (c8 ^ (r & 7))) * 8] = *(const u16x8*)(kb + qkbase + (size_t)p * 8);
  }
  // sS staging (Spref rows [e][d] bf16 + z row 64 + zero rows 65..79)
#pragma unroll
  for (int i = 0; i < 2; ++i) {
    int p = t * 2 + i, e = p >> 3, c8 = p & 7;
    *(u16x8*)&sS[(e * 8 + (c8 ^ (e & 7))) * 8] = *(const u16x8*)(Spref + sbase + (size_t)p * 8);
  }
  if (t < 64) sS[64 * 64 + t] = f2bf(zpref[((size_t)bh * 32 + c) * 64 + t]);
  {
    unsigned int* zz = (unsigned int*)&sS[65 * 64];
    for (int i = t; i < 480; i += 256) zz[i] = 0u;
  }
  // v^T scatter into svt (row e, col s; swizzle &15)
#pragma unroll
  for (int i = 0; i < 4; ++i) {
    int p = t * 4 + i, s = p >> 3, e0g = (p & 7) * 8;
#pragma unroll
    for (int j = 0; j < 8; ++j) {
      int e = e0g + j;
      svt[(e * 16 + ((s >> 3) ^ (e & 15))) * 8 + (s & 7)] = vreg[i][j];
    }
  }

  int rowbase = w * 32;
  // q fragments direct from global (row-contig 16B, L2-hot, 1 wave per row)
  bf16x8 aq[2][2];
#pragma unroll
  for (int mi = 0; mi < 2; ++mi)
#pragma unroll
    for (int kt = 0; kt < 2; ++kt) {
      int r = rowbase + mi * 16 + fr;
      aq[mi][kt] = *(const bf16x8*)(qb + qkbase + (size_t)r * 64 + kt * 32 + fq * 8);
    }
  __syncthreads();  // barrier 1: sk/svt/sS ready

  // swapped QK^T from sk: accsT[mi][ni] = C[s-tile ni][m-tile mi]; lane holds
  // P[s = ni*16+fq*4+j][m = rowbase+mi*16+fr]
  f32x4 accsT[2][8];
  f32x4 z4 = {0.f, 0.f, 0.f, 0.f};
#pragma unroll
  for (int mi = 0; mi < 2; ++mi)
#pragma unroll
    for (int ni = 0; ni < 8; ++ni) accsT[mi][ni] = z4;

#pragma unroll
  for (int ni = 0; ni < 8; ++ni)
#pragma unroll
    for (int kt = 0; kt < 2; ++kt) {
      int r = ni * 16 + fr;
      int c8 = (kt * 4 + fq) ^ (r & 7);
      bf16x8 bk = *(const bf16x8*)&sk[(r * 8 + c8) * 8];
      accsT[0][ni] = __builtin_amdgcn_mfma_f32_16x16x32_bf16(bk, aq[0][kt], accsT[0][ni], 0, 0, 0);
      accsT[1][ni] = __builtin_amdgcn_mfma_f32_16x16x32_bf16(bk, aq[1][kt], accsT[1][ni], 0, 0, 0);
    }

  // in-register causal mask + rowsum (per lane: m = rowbase+mi*16+fr)
  float rs[2];
#pragma unroll
  for (int mi = 0; mi < 2; ++mi) {
    int m16 = mi * 16 + fr;        // m - rowbase
    float sum = 0.f;
#pragma unroll
    for (int ni = 0; ni < 8; ++ni)
#pragma unroll
      for (int j = 0; j < 4; ++j) {
        int s = ni * 16 + fq * 4 + j - rowbase;  // s - rowbase
        float v = (s <= m16) ? accsT[mi][ni][j] : 0.f;
        accsT[mi][ni][j] = v;
        sum += v;
      }
    sum += __shfl_xor(sum, 16, 64);
    sum += __shfl_xor(sum, 32, 64);
    rs[mi] = sum;
  }

  // P -> ss as packed b32 pairs: addr chunk (2ni+(fq>>1))^(m&15), off (fq&1)*4+2p
#pragma unroll
  for (int mi = 0; mi < 2; ++mi) {
    int m = rowbase + mi * 16 + fr;
#pragma unroll
    for (int ni = 0; ni < 8; ++ni)
#pragma unroll
      for (int p = 0; p < 2; ++p) {
        unsigned int pk = (unsigned int)f2bf(accsT[mi][ni][2 * p]) |
                          ((unsigned int)f2bf(accsT[mi][ni][2 * p + 1]) << 16);
        int chunk = (2 * ni + (fq >> 1)) ^ (m & 15);
        *(unsigned int*)&ss[m * 128 + chunk * 8 + (fq & 1) * 4 + 2 * p] = pk;
      }
  }
  __syncthreads();  // barrier 2: ss ready

  f32x4 acco[2][4];
  f32x4 accd[2];
#pragma unroll
  for (int mi = 0; mi < 2; ++mi) {
    accd[mi] = z4;
#pragma unroll
    for (int ni = 0; ni < 4; ++ni) acco[mi][ni] = z4;
  }
  // inter-chunk: q @ S (+ den column from z row)
#pragma unroll
  for (int kt = 0; kt < 2; ++kt) {
#pragma unroll
    for (int ni = 0; ni < 4; ++ni) {
      int r = ni * 16 + fr;
      int c8 = (kt * 4 + fq) ^ (r & 7);
      bf16x8 bS = *(const bf16x8*)&sS[(r * 8 + c8) * 8];
      acco[0][ni] = __builtin_amdgcn_mfma_f32_16x16x32_bf16(aq[0][kt], bS, acco[0][ni], 0, 0, 0);
      acco[1][ni] = __builtin_amdgcn_mfma_f32_16x16x32_bf16(aq[1][kt], bS, acco[1][ni], 0, 0, 0);
    }
    {
      int r = 64 + fr;
      int c8 = (kt * 4 + fq) ^ (r & 7);
      bf16x8 bz = *(const bf16x8*)&sS[(r * 8 + c8) * 8];
      accd[0] = __builtin_amdgcn_mfma_f32_16x16x32_bf16(aq[0][kt], bz, accd[0], 0, 0, 0);
      accd[1] = __builtin_amdgcn_mfma_f32_16x16x32_bf16(aq[1][kt], bz, accd[1], 0, 0, 0);
    }
  }
  // intra-chunk: masked P @ v
#pragma unroll
  for (int kt = 0; kt < 4; ++kt) {
    bf16x8 am[2];
#pragma unroll
    for (int mi = 0; mi < 2; ++mi) {
      int r = rowbase + mi * 16 + fr;
      int c8 = (kt * 4 + fq) ^ (r & 15);
      am[mi] = *(const bf16x8*)&ss[(r * 16 + c8) * 8];
    }
#pragma unroll
    for (int ni = 0; ni < 4; ++ni) {
      int r = ni * 16 + fr;
      int c8 = (kt * 4 + fq) ^ (r & 15);
      bf16x8 bv = *(const bf16x8*)&svt[(r * 16 + c8) * 8];
      acco[0][ni] = __builtin_amdgcn_mfma_f32_16x16x32_bf16(am[0], bv, acco[0][ni], 0, 0, 0);
      acco[1][ni] = __builtin_amdgcn_mfma_f32_16x16x32_bf16(am[1], bv, acco[1][ni], 0, 0, 0);
    }
  }

  int b = bh >> 4, h = bh & 15;
#pragma unroll
  for (int mi = 0; mi < 2; ++mi)
#pragma unroll
    for (int j = 0; j < 4; ++j) {
      float rsj = __shfl(rs[mi], fq * 4 + j, 64);  // rowsum for m16 = fq*4+j
      float den = __shfl(accd[mi][j], (lane & 48), 64) + rsj;
      float rden = 1.f / den;
      int m = rowbase + mi * 16 + fq * 4 + j;
      size_t rowoff = ((size_t)b * 4096 + (size_t)c * 128 + m) * 1024 + h * 64;
#pragma unroll
      for (int ni = 0; ni < 4; ++ni) {
        int e = ni * 16 + fr;
        float o = acco[mi][ni][j] * rden + 1e-12f;
        attn[rowoff + e] = f2bf(o);
      }
    }
}

// ---------------- host launch ------------------------------------------------
extern "C" void kernel_launch(void* const* d_in, const int* in_sizes, int n_in,
                              void* d_out, int out_size, void* d_ws, size_t ws_size,
                              hipStream_t stream) {
  (void)in_sizes; (void)n_in; (void)out_size; (void)ws_size;
  const float* x = (const float*)d_in[0];
  const float* Wq = (const float*)d_in[1];
  const float* Wk = (const float*)d_in[2];
  const float* Wv = (const float*)d_in[3];
  const float* Wo = (const float*)d_in[4];
  char* ws = (char*)d_ws;
  unsigned short* xbf  = (unsigned short*)(ws + 0);          // 33554432 B
  unsigned short* wqkv = (unsigned short*)(ws + 33554432);   // 6291456 B
  unsigned short* wo   = (unsigned short*)(ws + 39845888);   // 2097152 B
  unsigned short* q    = (unsigned short*)(ws + 41943040);   // 33554432 B
  unsigned short* k    = (unsigned short*)(ws + 75497472);   // 33554432 B
  unsigned short* v    = (unsigned short*)(ws + 109051904);  // 33554432 B
  unsigned short* attn = (unsigned short*)(ws + 142606336);  // 33554432 B
  float* Sbuf          = (float*)(ws + 176160768);           // 33554432 B
  unsigned short* Spref= (unsigned short*)(ws + 209715200);  // 16777216 B
  float* zbuf          = (float*)(ws + 226492416);           // 524288 B
  float* zpref         = (float*)(ws + 227016704);           // 524288 B

  cast_all<<<10240, 256, 0, stream>>>(x, Wq, Wk, Wv, Wo, xbf, wqkv, wo);
  gemm_bt<1><<<3072, 256, 0, stream>>>(xbf, wqkv, nullptr, q, k, v, 1024, 3072, 24);
  chunk_state<<<2048, 256, 0, stream>>>(k, v, Sbuf, zbuf);
  scan_all<<<1040, 256, 0, stream>>>(Sbuf, zbuf, Spref, zpref);
  chunk_out<<<2048, 256, 0, stream>>>(q, k, v, Spref, zpref, attn);
  gemm_bt<0><<<1024, 256, 0, stream>>>(attn, wo, d_out, nullptr, nullptr, nullptr, 1024, 1024, 8);
}

// Round 10
// 227.793 us; speedup vs baseline: 1.0897x; 1.0596x over previous
//
#include <hip/hip_runtime.h>
#include <stdint.h>

typedef float f32x4 __attribute__((ext_vector_type(4)));
typedef __bf16 bf16x8 __attribute__((ext_vector_type(8)));
typedef unsigned short u16x8 __attribute__((ext_vector_type(8)));

#define DEV __device__ __forceinline__

DEV unsigned short f2bf(float f) {
  unsigned int u = __float_as_uint(f);
  unsigned int r = (u + 0x7FFFu + ((u >> 16) & 1u)) >> 16;
  return (unsigned short)r;
}
DEV float b2f(unsigned short h) { return __uint_as_float(((unsigned int)h) << 16); }

DEV void gload16(const void* g, void* l) {
  __builtin_amdgcn_global_load_lds((__attribute__((address_space(1))) void*)(g),
                                   (__attribute__((address_space(3))) void*)(l), 16, 0, 0);
}

// ---------------- all casts fused: x (2M units) + 4 weights (512K units) ----
__global__ void cast_all(const float* __restrict__ x, const float* __restrict__ Wq,
                         const float* __restrict__ Wk, const float* __restrict__ Wv,
                         const float* __restrict__ Wo, unsigned short* __restrict__ xbf,
                         unsigned short* __restrict__ wqkv, unsigned short* __restrict__ wo) {
  int i = blockIdx.x * 256 + threadIdx.x;
  const float* src;
  unsigned short* dst;
  int j;
  if (i < 2097152) {
    src = x; dst = xbf; j = i;
  } else {
    int k = i - 2097152;           // 524288 units
    int sel = k >> 17; j = k & 131071;
    src = (sel == 0) ? Wq : (sel == 1) ? Wk : (sel == 2) ? Wv : Wo;
    dst = (sel < 3) ? (wqkv + (size_t)sel * 1048576) : wo;
  }
  const float4* p = (const float4*)src + (size_t)j * 2;
  float4 a = p[0], b = p[1];
  u16x8 o;
  o[0] = f2bf(a.x); o[1] = f2bf(a.y); o[2] = f2bf(a.z); o[3] = f2bf(a.w);
  o[4] = f2bf(b.x); o[5] = f2bf(b.y); o[6] = f2bf(b.z); o[7] = f2bf(b.w);
  ((u16x8*)dst)[j] = o;
}

// ---------------- bf16 GEMM, B^T layout (out[m,n] = sum_k A[m,k]*W[n,k]) ----
// 128x128 tile, BK=64, multi-block/CU implicit overlap. No XCD swizzle
// (r4/r5 A/B: swizzle FETCH 143->210MB, +3.5% time). A bf16 via gload_lds
// (r6 A/B: fp32 reg-staged fused cast = 104->180us regression).
template<int MODE>
__global__ __launch_bounds__(256, 2) void gemm_bt(
    const unsigned short* __restrict__ A, const unsigned short* __restrict__ Bw,
    void* __restrict__ out0, unsigned short* __restrict__ qp,
    unsigned short* __restrict__ kp, unsigned short* __restrict__ vp,
    int K, int N, int nTn)
{
  __shared__ unsigned short sA[128 * 64];
  __shared__ unsigned short sB[128 * 64];
  int t = threadIdx.x, w = t >> 6, lane = t & 63, fr = lane & 15, fq = lane >> 4;
  int bid = blockIdx.x;
  int bm = bid / nTn, bn = bid % nTn;
  int wm = w >> 1, wn = w & 1;

  f32x4 acc[4][4];
  f32x4 z4 = {0.f, 0.f, 0.f, 0.f};
#pragma unroll
  for (int mi = 0; mi < 4; ++mi)
#pragma unroll
    for (int ni = 0; ni < 4; ++ni) acc[mi][ni] = z4;

  for (int k0 = 0; k0 < K; k0 += 64) {
#pragma unroll
    for (int i = 0; i < 4; ++i) {
      int p = (i * 4 + w) * 64 + lane;
      int r = p >> 3;
      int c8 = (p & 7) ^ (r & 7);  // inverse-swizzled source column-chunk
      gload16(A + (size_t)(bm * 128 + r) * K + k0 + c8 * 8, &sA[(i * 4 + w) * 512]);
      gload16(Bw + (size_t)(bn * 128 + r) * K + k0 + c8 * 8, &sB[(i * 4 + w) * 512]);
    }
    __syncthreads();
#pragma unroll
    for (int ks = 0; ks < 2; ++ks) {
      bf16x8 af[4], bg[4];
#pragma unroll
      for (int mi = 0; mi < 4; ++mi) {
        int r = wm * 64 + mi * 16 + fr;
        int c8 = (ks * 4 + fq) ^ (r & 7);
        af[mi] = *(const bf16x8*)&sA[(r * 8 + c8) * 8];
      }
#pragma unroll
      for (int ni = 0; ni < 4; ++ni) {
        int r = wn * 64 + ni * 16 + fr;
        int c8 = (ks * 4 + fq) ^ (r & 7);
        bg[ni] = *(const bf16x8*)&sB[(r * 8 + c8) * 8];
      }
#pragma unroll
      for (int mi = 0; mi < 4; ++mi)
#pragma unroll
        for (int ni = 0; ni < 4; ++ni)
          acc[mi][ni] = __builtin_amdgcn_mfma_f32_16x16x32_bf16(af[mi], bg[ni], acc[mi][ni], 0, 0, 0);
    }
    __syncthreads();
  }

  if (MODE == 0) {
    float* O = (float*)out0;
#pragma unroll
    for (int mi = 0; mi < 4; ++mi)
#pragma unroll
      for (int ni = 0; ni < 4; ++ni)
#pragma unroll
        for (int j = 0; j < 4; ++j) {
          int m = bm * 128 + wm * 64 + mi * 16 + fq * 4 + j;
          int n = bn * 128 + wn * 64 + ni * 16 + fr;
          O[(size_t)m * N + n] = acc[mi][ni][j];
        }
  } else {
    int tsel = (bn * 128) >> 10;  // 0:Q 1:K 2:V (whole block in one tensor)
    unsigned short* base = (tsel == 0) ? qp : ((tsel == 1) ? kp : vp);
#pragma unroll
    for (int mi = 0; mi < 4; ++mi)
#pragma unroll
      for (int ni = 0; ni < 4; ++ni)
#pragma unroll
        for (int j = 0; j < 4; ++j) {
          int m = bm * 128 + wm * 64 + mi * 16 + fq * 4 + j;  // b*4096 + l
          int n = bn * 128 + wn * 64 + ni * 16 + fr;
          int col1 = n & 1023;
          int h = col1 >> 6, d = col1 & 63;
          int b = m >> 12, l = m & 4095;
          float v = acc[mi][ni][j];
          if (tsel < 2) v = (v > 0.f) ? (v + 1.f) : __expf(v);  // elu(v)+1
          base[(((size_t)(b * 16 + h)) * 4096 + l) * 64 + d] = f2bf(v);
        }
  }
}

// ---------------- pass 1: per-chunk state via MFMA ---------------------------
// S_c[e][d] = sum_s v[s][e]*k[s][d], written DIRECTLY as bf16 into Spref slots
// (scan pass converts in-place to exclusive prefix). z_c[d] = sum_s k[s][d].
__global__ __launch_bounds__(256) void chunk_state(
    const unsigned short* __restrict__ kb, const unsigned short* __restrict__ vb,
    unsigned short* __restrict__ Spref, float* __restrict__ zbuf)
{
  __shared__ unsigned short kT[64 * 136];
  __shared__ unsigned short vT[64 * 136];
  int t = threadIdx.x, w = t >> 6, lane = t & 63, fr = lane & 15, fq = lane >> 4;
  int bh = blockIdx.x >> 5, c = blockIdx.x & 31;
  size_t base = ((size_t)bh * 4096 + (size_t)c * 128) * 64;

  int s = t >> 1, d0 = (t & 1) * 32;
  const unsigned short* kpp = kb + base + (size_t)s * 64 + d0;
  const unsigned short* vpp = vb + base + (size_t)s * 64 + d0;
#pragma unroll
  for (int i = 0; i < 4; ++i) {
    u16x8 kr = *(const u16x8*)(kpp + i * 8);
    u16x8 vr = *(const u16x8*)(vpp + i * 8);
#pragma unroll
    for (int j = 0; j < 8; ++j) {
      int d = d0 + i * 8 + j;
      kT[d * 136 + s] = kr[j];
      vT[d * 136 + s] = vr[j];
    }
  }
  __syncthreads();

  f32x4 acc[4];
  f32x4 z4 = {0.f, 0.f, 0.f, 0.f};
#pragma unroll
  for (int n = 0; n < 4; ++n) acc[n] = z4;
#pragma unroll
  for (int ks = 0; ks < 4; ++ks) {
    bf16x8 av = *(const bf16x8*)&vT[(w * 16 + fr) * 136 + ks * 32 + fq * 8];
#pragma unroll
    for (int n = 0; n < 4; ++n) {
      bf16x8 bk = *(const bf16x8*)&kT[(n * 16 + fr) * 136 + ks * 32 + fq * 8];
      acc[n] = __builtin_amdgcn_mfma_f32_16x16x32_bf16(av, bk, acc[n], 0, 0, 0);
    }
  }
  size_t ob = ((size_t)bh * 32 + c) * 4096;
#pragma unroll
  for (int n = 0; n < 4; ++n)
#pragma unroll
    for (int j = 0; j < 4; ++j) {
      int e = w * 16 + fq * 4 + j, dd = n * 16 + fr;
      Spref[ob + (size_t)e * 64 + dd] = f2bf(acc[n][j]);
    }
  if (t < 64) {
    float z = 0.f;
#pragma unroll
    for (int i = 0; i < 16; ++i) {
      u16x8 kr = *(const u16x8*)&kT[t * 136 + i * 8];
#pragma unroll
      for (int j = 0; j < 8; ++j) z += b2f(kr[j]);
    }
    zbuf[((size_t)bh * 32 + c) * 64 + t] = z;
  }
}

// ---------------- pass 2: IN-PLACE exclusive prefix over 32 chunks -----------
// S: packed 2 bf16/thread (u32), 131072 sequences; then z (fp32, 4096 seqs).
__global__ __launch_bounds__(256) void scan_all(
    unsigned short* __restrict__ Spref, const float* __restrict__ zbuf,
    float* __restrict__ zpref)
{
  if (blockIdx.x < 512) {
    int idx = blockIdx.x * 256 + threadIdx.x;   // 131072 u32 columns
    int bh = idx >> 11, i = idx & 2047;
    unsigned int* p32 = (unsigned int*)Spref;
    size_t base = (size_t)bh * 32 * 2048 + i;
    float r0 = 0.f, r1 = 0.f;
#pragma unroll
    for (int c = 0; c < 32; ++c) {
      unsigned int v = p32[base + (size_t)c * 2048];
      float v0 = b2f((unsigned short)(v & 0xFFFFu));
      float v1 = b2f((unsigned short)(v >> 16));
      p32[base + (size_t)c * 2048] =
          (unsigned int)f2bf(r0) | ((unsigned int)f2bf(r1) << 16);
      r0 += v0; r1 += v1;
    }
  } else {
    int idx = (blockIdx.x - 512) * 256 + threadIdx.x;  // 4096 sequences
    size_t base = (size_t)(idx >> 6) * 32 * 64 + (idx & 63);
    float run = 0.f;
#pragma unroll
    for (int c = 0; c < 32; ++c) {
      float v = zbuf[base + c * 64];
      zpref[base + c * 64] = run;
      run += v;
    }
  }
}

// ---------------- pass 3: per-chunk output (v2 — best measured) --------------
// swapped QK^T (C[s][m]) -> in-register causal mask, 2-shfl rowsum,
// P->LDS as b32 pair writes. q,k staged in LDS; skv reused k -> v^T.
__global__ __launch_bounds__(256, 2) void chunk_out(
    const unsigned short* __restrict__ qb, const unsigned short* __restrict__ kb,
    const unsigned short* __restrict__ vb, const unsigned short* __restrict__ Spref,
    const float* __restrict__ zpref, unsigned short* __restrict__ attn)
{
  __shared__ unsigned short sq[128 * 64];   // q, swizzled (&7)
  __shared__ unsigned short skv[128 * 64];  // k (swz &7), then v^T [64][128] (swz &15)
  __shared__ unsigned short ss[128 * 128];  // P bf16 [m][s] (swz &15)
  __shared__ unsigned short sS[80 * 64];    // state rows e=0..63, z at 64, zeros 65..79
  int t = threadIdx.x, w = t >> 6, lane = t & 63, fr = lane & 15, fq = lane >> 4;
  int bh = blockIdx.x >> 5, c = blockIdx.x & 31;
  size_t qkbase = ((size_t)bh * 4096 + (size_t)c * 128) * 64;
  size_t sbase = ((size_t)bh * 32 + c) * 4096;

  u16x8 vreg[4];  // v chunk staged to regs early (T14-style)
#pragma unroll
  for (int i = 0; i < 4; ++i)
    vreg[i] = *(const u16x8*)(vb + qkbase + (size_t)(t * 4 + i) * 8);

#pragma unroll
  for (int i = 0; i < 4; ++i) {
    int p = t * 4 + i, r = p >> 3, c8 = p & 7;
    int sw = (r * 8 + (c8 ^ (r & 7))) * 8;
    *(u16x8*)&sq[sw] = *(const u16x8*)(qb + qkbase + (size_t)p * 8);
    *(u16x8*)&skv[sw] = *(const u16x8*)(kb + qkbase + (size_t)p * 8);
  }
#pragma unroll
  for (int i = 0; i < 2; ++i) {
    int p = t * 2 + i, e = p >> 3, c8 = p & 7;
    *(u16x8*)&sS[(e * 8 + (c8 ^ (e & 7))) * 8] = *(const u16x8*)(Spref + sbase + (size_t)p * 8);
  }
  if (t < 64) sS[64 * 64 + t] = f2bf(zpref[((size_t)bh * 32 + c) * 64 + t]);
  {
    unsigned int* zz = (unsigned int*)&sS[65 * 64];
    for (int i = t; i < 480; i += 256) zz[i] = 0u;
  }
  __syncthreads();

  int rowbase = w * 32;
  bf16x8 aq[2][2];
#pragma unroll
  for (int mi = 0; mi < 2; ++mi)
#pragma unroll
    for (int kt = 0; kt < 2; ++kt) {
      int r = rowbase + mi * 16 + fr;
      int c8 = (kt * 4 + fq) ^ (r & 7);
      aq[mi][kt] = *(const bf16x8*)&sq[(r * 8 + c8) * 8];
    }

  // swapped QK^T: accsT[mi][ni] = C[s-tile ni][m-tile mi]; lane holds
  // P[s = ni*16+fq*4+j][m = rowbase+mi*16+fr]
  f32x4 accsT[2][8];
  f32x4 z4 = {0.f, 0.f, 0.f, 0.f};
#pragma unroll
  for (int mi = 0; mi < 2; ++mi)
#pragma unroll
    for (int ni = 0; ni < 8; ++ni) accsT[mi][ni] = z4;

#pragma unroll
  for (int ni = 0; ni < 8; ++ni)
#pragma unroll
    for (int kt = 0; kt < 2; ++kt) {
      int r = ni * 16 + fr;
      int c8 = (kt * 4 + fq) ^ (r & 7);
      bf16x8 bk = *(const bf16x8*)&skv[(r * 8 + c8) * 8];
      accsT[0][ni] = __builtin_amdgcn_mfma_f32_16x16x32_bf16(bk, aq[0][kt], accsT[0][ni], 0, 0, 0);
      accsT[1][ni] = __builtin_amdgcn_mfma_f32_16x16x32_bf16(bk, aq[1][kt], accsT[1][ni], 0, 0, 0);
    }

  // in-register causal mask + rowsum (per lane: m = rowbase+mi*16+fr)
  float rs[2];
#pragma unroll
  for (int mi = 0; mi < 2; ++mi) {
    int m16 = mi * 16 + fr;        // m - rowbase
    float sum = 0.f;
#pragma unroll
    for (int ni = 0; ni < 8; ++ni)
#pragma unroll
      for (int j = 0; j < 4; ++j) {
        int s = ni * 16 + fq * 4 + j - rowbase;  // s - rowbase
        float v = (s <= m16) ? accsT[mi][ni][j] : 0.f;
        accsT[mi][ni][j] = v;
        sum += v;
      }
    sum += __shfl_xor(sum, 16, 64);
    sum += __shfl_xor(sum, 32, 64);
    rs[mi] = sum;
  }
  __syncthreads();  // all waves done reading k from skv

  // write v^T into skv (row e, col s; swizzle &15)
#pragma unroll
  for (int i = 0; i < 4; ++i) {
    int p = t * 4 + i, s = p >> 3, e0g = (p & 7) * 8;
#pragma unroll
    for (int j = 0; j < 8; ++j) {
      int e = e0g + j;
      skv[(e * 16 + ((s >> 3) ^ (e & 15))) * 8 + (s & 7)] = vreg[i][j];
    }
  }
  // P -> ss as packed b32 pairs: addr chunk (2ni+(fq>>1))^(m&15), off (fq&1)*4+2p
#pragma unroll
  for (int mi = 0; mi < 2; ++mi) {
    int m = rowbase + mi * 16 + fr;
#pragma unroll
    for (int ni = 0; ni < 8; ++ni)
#pragma unroll
      for (int p = 0; p < 2; ++p) {
        unsigned int pk = (unsigned int)f2bf(accsT[mi][ni][2 * p]) |
                          ((unsigned int)f2bf(accsT[mi][ni][2 * p + 1]) << 16);
        int chunk = (2 * ni + (fq >> 1)) ^ (m & 15);
        *(unsigned int*)&ss[m * 128 + chunk * 8 + (fq & 1) * 4 + 2 * p] = pk;
      }
  }
  __syncthreads();

  f32x4 acco[2][4];
  f32x4 accd[2];
#pragma unroll
  for (int mi = 0; mi < 2; ++mi) {
    accd[mi] = z4;
#pragma unroll
    for (int ni = 0; ni < 4; ++ni) acco[mi][ni] = z4;
  }
  // inter-chunk: q @ S (+ den column from z row)
#pragma unroll
  for (int kt = 0; kt < 2; ++kt) {
#pragma unroll
    for (int ni = 0; ni < 4; ++ni) {
      int r = ni * 16 + fr;
      int c8 = (kt * 4 + fq) ^ (r & 7);
      bf16x8 bS = *(const bf16x8*)&sS[(r * 8 + c8) * 8];
      acco[0][ni] = __builtin_amdgcn_mfma_f32_16x16x32_bf16(aq[0][kt], bS, acco[0][ni], 0, 0, 0);
      acco[1][ni] = __builtin_amdgcn_mfma_f32_16x16x32_bf16(aq[1][kt], bS, acco[1][ni], 0, 0, 0);
    }
    {
      int r = 64 + fr;
      int c8 = (kt * 4 + fq) ^ (r & 7);
      bf16x8 bz = *(const bf16x8*)&sS[(r * 8 + c8) * 8];
      accd[0] = __builtin_amdgcn_mfma_f32_16x16x32_bf16(aq[0][kt], bz, accd[0], 0, 0, 0);
      accd[1] = __builtin_amdgcn_mfma_f32_16x16x32_bf16(aq[1][kt], bz, accd[1], 0, 0, 0);
    }
  }
  // intra-chunk: masked P @ v
#pragma unroll
  for (int kt = 0; kt < 4; ++kt) {
    bf16x8 am[2];
#pragma unroll
    for (int mi = 0; mi < 2; ++mi) {
      int r = rowbase + mi * 16 + fr;
      int c8 = (kt * 4 + fq) ^ (r & 15);
      am[mi] = *(const bf16x8*)&ss[(r * 16 + c8) * 8];
    }
#pragma unroll
    for (int ni = 0; ni < 4; ++ni) {
      int r = ni * 16 + fr;
      int c8 = (kt * 4 + fq) ^ (r & 15);
      bf16x8 bv = *(const bf16x8*)&skv[(r * 16 + c8) * 8];
      acco[0][ni] = __builtin_amdgcn_mfma_f32_16x16x32_bf16(am[0], bv, acco[0][ni], 0, 0, 0);
      acco[1][ni] = __builtin_amdgcn_mfma_f32_16x16x32_bf16(am[1], bv, acco[1][ni], 0, 0, 0);
    }
  }

  int b = bh >> 4, h = bh & 15;
#pragma unroll
  for (int mi = 0; mi < 2; ++mi)
#pragma unroll
    for (int j = 0; j < 4; ++j) {
      float rsj = __shfl(rs[mi], fq * 4 + j, 64);  // rowsum for m16 = fq*4+j
      float den = __shfl(accd[mi][j], (lane & 48), 64) + rsj;
      float rden = 1.f / den;
      int m = rowbase + mi * 16 + fq * 4 + j;
      size_t rowoff = ((size_t)b * 4096 + (size_t)c * 128 + m) * 1024 + h * 64;
#pragma unroll
      for (int ni = 0; ni < 4; ++ni) {
        int e = ni * 16 + fr;
        float o = acco[mi][ni][j] * rden + 1e-12f;
        attn[rowoff + e] = f2bf(o);
      }
    }
}

// ---------------- host launch ------------------------------------------------
extern "C" void kernel_launch(void* const* d_in, const int* in_sizes, int n_in,
                              void* d_out, int out_size, void* d_ws, size_t ws_size,
                              hipStream_t stream) {
  (void)in_sizes; (void)n_in; (void)out_size; (void)ws_size;
  const float* x = (const float*)d_in[0];
  const float* Wq = (const float*)d_in[1];
  const float* Wk = (const float*)d_in[2];
  const float* Wv = (const float*)d_in[3];
  const float* Wo = (const float*)d_in[4];
  char* ws = (char*)d_ws;
  unsigned short* xbf  = (unsigned short*)(ws + 0);          // 33554432 B
  unsigned short* wqkv = (unsigned short*)(ws + 33554432);   // 6291456 B
  unsigned short* wo   = (unsigned short*)(ws + 39845888);   // 2097152 B
  unsigned short* q    = (unsigned short*)(ws + 41943040);   // 33554432 B
  unsigned short* k    = (unsigned short*)(ws + 75497472);   // 33554432 B
  unsigned short* v    = (unsigned short*)(ws + 109051904);  // 33554432 B
  unsigned short* attn = (unsigned short*)(ws + 142606336);  // 33554432 B
  unsigned short* Spref= (unsigned short*)(ws + 176160768);  // 16777216 B (chunk states -> in-place prefix)
  float* zbuf          = (float*)(ws + 192937984);           // 524288 B
  float* zpref         = (float*)(ws + 193462272);           // 524288 B

  cast_all<<<10240, 256, 0, stream>>>(x, Wq, Wk, Wv, Wo, xbf, wqkv, wo);
  gemm_bt<1><<<3072, 256, 0, stream>>>(xbf, wqkv, nullptr, q, k, v, 1024, 3072, 24);
  chunk_state<<<2048, 256, 0, stream>>>(k, v, Spref, zbuf);
  scan_all<<<528, 256, 0, stream>>>(Spref, zbuf, zpref);
  chunk_out<<<2048, 256, 0, stream>>>(q, k, v, Spref, zpref, attn);
  gemm_bt<0><<<1024, 256, 0, stream>>>(attn, wo, d_out, nullptr, nullptr, nullptr, 1024, 1024, 8);
}